// Round 9
// baseline (78.021 us; speedup 1.0000x reference)
//
#include <hip/hip_runtime.h>

// VQC 12-qubit statevector, batch=1024. R9: TWO batch elements per block
// (grid 512, 128 threads, 2 waves), each thread holds aA[32]+aB[32].
// R8 post-mortem: PAD=62 aliased rows (exchange rows are 64 entries wide;
// PAD is row STRIDE and must be >=64). Fix: keep PAD=66 and share ONE
// 64x66 buffer SEQUENTIALLY between the two streams inside each exchange
// (AB: 2 wave-local lgkm drains; BA: 4 block barriers). All theta-only work
// (table, fused_z chains, alpha sincos) and all barrier/drain fixed costs
// are shared by both elements; only encoding + gate FMAs duplicate, and the
// dual streams give in-wave ILP to fill latency bubbles.
//
// Layouts per element (unchanged from R6/R7):
//   A: b11=w(q0), b10..b6=reg(q1..q5), b5..b0=lane(q6..q11)
//   B: b11=w(q0), b10..b5=lane(q1..q6), b4..b0=reg(q7..q11)
// Per layer: Y q1..5 reg [A]; A->B exch (fuses Y_q6; wave-local); Y q7..11
// reg [B]; fused Z; B->A exch (fuses CNOT-chain perm + next layer's Y_q0).
// Layer-0 Y_q0 folded into closed-form encoding; layer-2 Zs dropped.
//
// LDS: buf 64*66 v2f = 33,792B + thTab 368B + redBuf 192B = 34,352B
// -> 4 blocks/CU. __launch_bounds__(128) only (no min-wave clamp; R1 lesson).

#define PI_F 3.14159265358979323846f
#define NR 32
#define PAD 66   // row stride: 64 entries + skew 2; b128 pairs stay 16B-aligned

typedef __attribute__((ext_vector_type(2))) float v2f;
typedef __attribute__((ext_vector_type(4))) float v4f;

__device__ __forceinline__ v2f mkv(float x, float y) { v2f r; r.x = x; r.y = y; return r; }
__device__ __forceinline__ v2f cmul(v2f a, v2f b) {   // complex a*b
    return a.x * b + a.y * mkv(-b.y, b.x);
}
__device__ __forceinline__ v2f cmulc(v2f a, v2f b) {  // a * conj(b)
    return a.x * mkv(b.x, -b.y) + a.y * mkv(b.y, b.x);
}

// ---- cross-lane xor primitives (readout only) ----
template<int M>
__device__ __forceinline__ float lane_xor_f(float v) {
    if constexpr (M == 1) {        // quad_perm [1,0,3,2]
        return __int_as_float(__builtin_amdgcn_update_dpp(
            0, __float_as_int(v), 0xB1, 0xF, 0xF, false));
    } else if constexpr (M == 2) { // quad_perm [2,3,0,1]
        return __int_as_float(__builtin_amdgcn_update_dpp(
            0, __float_as_int(v), 0x4E, 0xF, 0xF, false));
    } else if constexpr (M == 4) {
        return __int_as_float(__builtin_amdgcn_ds_swizzle(__float_as_int(v), 0x101F));
    } else if constexpr (M == 8) {
        return __int_as_float(__builtin_amdgcn_ds_swizzle(__float_as_int(v), 0x201F));
    } else if constexpr (M == 16) {
        return __int_as_float(__builtin_amdgcn_ds_swizzle(__float_as_int(v), 0x401F));
    } else {                       // M == 32: cross-half
        return __shfl_xor(v, 32, 64);
    }
}

// One Y reg-gate stage applied to BOTH streams (interleaved for ILP).
template<int RB>
__device__ __forceinline__ void ypow_reg2(v2f (&aA)[NR], v2f (&aB)[NR],
                                          float c, float s) {
    #pragma unroll
    for (int r0 = 0; r0 < NR; ++r0) {
        if ((r0 >> RB) & 1) continue;
        const int r1 = r0 | (1 << RB);
        v2f A0 = aA[r0], A1 = aA[r1];
        v2f B0 = aB[r0], B1 = aB[r1];
        aA[r0] = c * A0 - s * A1;
        aA[r1] = s * A0 + c * A1;
        aB[r0] = c * B0 - s * B1;
        aB[r1] = s * B0 + c * B1;
    }
}

// yt = &thTab[l*12]; layout A: q1..q5 -> reg bits 4..0
__device__ __forceinline__ void ypowA2(v2f (&aA)[NR], v2f (&aB)[NR],
                                       const v2f* __restrict__ yt) {
    { v2f t = yt[1]; ypow_reg2<4>(aA, aB, t.x, t.y); }
    { v2f t = yt[2]; ypow_reg2<3>(aA, aB, t.x, t.y); }
    { v2f t = yt[3]; ypow_reg2<2>(aA, aB, t.x, t.y); }
    { v2f t = yt[4]; ypow_reg2<1>(aA, aB, t.x, t.y); }
    { v2f t = yt[5]; ypow_reg2<0>(aA, aB, t.x, t.y); }
}
// layout B: q7..q11 -> reg bits 4..0
__device__ __forceinline__ void ypowB2(v2f (&aA)[NR], v2f (&aB)[NR],
                                       const v2f* __restrict__ yt) {
    { v2f t = yt[7];  ypow_reg2<4>(aA, aB, t.x, t.y); }
    { v2f t = yt[8];  ypow_reg2<3>(aA, aB, t.x, t.y); }
    { v2f t = yt[9];  ypow_reg2<2>(aA, aB, t.x, t.y); }
    { v2f t = yt[10]; ypow_reg2<1>(aA, aB, t.x, t.y); }
    { v2f t = yt[11]; ypow_reg2<0>(aA, aB, t.x, t.y); }
}

// A->B transpose, fusing Y on q6 (b5). Wave-local; ONE buffer shared
// sequentially: write/readA, then write/readB (same-wave DS ordering makes
// readA-then-writeB safe; memory clobber pins compiler issue order).
template<bool PRE_SYNC>
__device__ __forceinline__ void exchange_AB2(v2f (&aA)[NR], v2f (&aB)[NR],
                                             v2f* buf, int w, int lane,
                                             float c6, float s6) {
    v2f* wb = buf + w * (NR * PAD);
    if (PRE_SYNC) __syncthreads();         // prev BA's stream-B reads done
    const int wslot = (lane & 31) * 2 + (lane >> 5);
    const int g = lane >> 1;               // b10..b6 of output
    const float k0 = (lane & 1) ? s6 : c6;
    const float k1 = (lane & 1) ? c6 : -s6;
    // ---- stream A ----
    #pragma unroll
    for (int r = 0; r < NR; ++r)           // slot = [b10..b6 | b4..b0 | b5]
        wb[r * PAD + wslot] = aA[r];
    asm volatile("s_waitcnt lgkmcnt(0)" ::: "memory");
    #pragma unroll
    for (int r = 0; r < NR; ++r) {
        v4f p = *(const v4f*)(&wb[g * PAD + r * 2]);   // (b5=0, b5=1) pair
        aA[r] = k0 * p.xy + k1 * p.zw;
    }
    asm volatile("" ::: "memory");         // reads issued before overwrites
    // ---- stream B ----
    #pragma unroll
    for (int r = 0; r < NR; ++r)
        wb[r * PAD + wslot] = aB[r];
    asm volatile("s_waitcnt lgkmcnt(0)" ::: "memory");
    #pragma unroll
    for (int r = 0; r < NR; ++r) {
        v4f p = *(const v4f*)(&wb[g * PAD + r * 2]);
        aB[r] = k0 * p.xy + k1 * p.zw;
    }
}

// B->A transpose, fusing the CNOT-chain permutation (new[y] = old[y^(y>>1)])
// and the NEXT layer's Y_q0. Cross-wave; sequential buffer reuse (4 barriers).
__device__ __forceinline__ void exchange_BA2(v2f (&aA)[NR], v2f (&aB)[NR],
                                             v2f* buf, int w, int lane,
                                             float c0, float s0) {
    const int p6w = lane ^ (w << 5);       // (x10^x11)<<5 | x9..x5 for this writer
    const float k0 = w ? s0 : c0;
    const float k1 = w ? c0 : -s0;
    __syncthreads();                       // all waves' AB stream-B reads done
    // ---- stream A ----
    #pragma unroll
    for (int r = 0; r < NR; ++r)           // slot = p6*PAD + (x4..x0)*2 + x11
        buf[p6w * PAD + r * 2 + w] = aA[r];
    __syncthreads();
    #pragma unroll
    for (int rp = 0; rp < NR; ++rp) {
        const int ylow = (rp << 6) | lane;         // b10..b0 of output index
        const int t = ylow ^ (ylow >> 1);          // Gray inverse (11 bits)
        const int base = (t >> 5) * PAD + (t & 31) * 2;
        v4f p = *(const v4f*)(&buf[base]);         // (b11=0, b11=1) pair
        aA[rp] = k0 * p.xy + k1 * p.zw;
    }
    __syncthreads();                       // all stream-A reads done
    // ---- stream B ----
    #pragma unroll
    for (int r = 0; r < NR; ++r)
        buf[p6w * PAD + r * 2 + w] = aB[r];
    __syncthreads();
    #pragma unroll
    for (int rp = 0; rp < NR; ++rp) {
        const int ylow = (rp << 6) | lane;
        const int t = ylow ^ (ylow >> 1);
        const int base = (t >> 5) * PAD + (t & 31) * 2;
        v4f p = *(const v4f*)(&buf[base]);
        aB[rp] = k0 * p.xy + k1 * p.zw;
    }
}

// Fused Z for all 12 qubits, layout B, BOTH streams. Chain values (curs) are
// element-independent -> computed once, applied to both states.
__device__ __forceinline__ void fused_z2(v2f (&aA)[NR], v2f (&aB)[NR],
                                         int w, int lane,
                                         const float* __restrict__ th,
                                         const v2f* __restrict__ zt) {
    float alpha = w ? th[1] : 0.0f;
    #pragma unroll
    for (int k = 0; k < 6; ++k)                 // lane bit k <-> q(6-k)
        alpha += ((lane >> k) & 1) ? th[2*(6-k)+1] : 0.0f;
    float zs, zc; __sincosf(PI_F * alpha, &zs, &zc);
    v2f zq[5];
    #pragma unroll
    for (int j = 0; j < 5; ++j) zq[j] = zt[j];  // reg bit j <-> q(11-j)
    const v2f base = mkv(zc, zs);
    v2f curs[4];
    curs[0] = base;
    curs[1] = cmul(base, cmul(zq[2], zq[3]));   // g(8)  = 12
    curs[2] = cmul(base, cmul(zq[3], zq[4]));   // g(16) = 24
    curs[3] = cmul(base, cmul(zq[2], zq[4]));   // g(24) = 20
    aA[0]  = cmul(aA[0],  curs[0]); aB[0]  = cmul(aB[0],  curs[0]);
    aA[12] = cmul(aA[12], curs[1]); aB[12] = cmul(aB[12], curs[1]);
    aA[24] = cmul(aA[24], curs[2]); aB[24] = cmul(aB[24], curs[2]);
    aA[20] = cmul(aA[20], curs[3]); aB[20] = cmul(aB[20], curs[3]);
    #pragma unroll
    for (int i = 1; i < 8; ++i) {
        #pragma unroll
        for (int m = 0; m < 4; ++m) {
            const int k = 8 * m + i;
            const int bit = __builtin_ctz(i);
            const int g = k ^ (k >> 1);
            curs[m] = ((g >> bit) & 1) ? cmul(curs[m], zq[bit])
                                       : cmulc(curs[m], zq[bit]);
            aA[g] = cmul(aA[g], curs[m]);
            aB[g] = cmul(aB[g], curs[m]);
        }
    }
}

__global__ __launch_bounds__(128) void vqc_kernel(
    const float* __restrict__ inputs,   // [1024,12]
    const float* __restrict__ thetas,   // [72] = [3][12][2]
    float* __restrict__ out)            // [1024,12]
{
    __shared__ __align__(16) v2f buf[64 * PAD];   // 33,792 B, shared by streams
    __shared__ v2f thTab[46];                     // 36 Y pairs + 10 Z pairs
    __shared__ float redBuf[2][24];

    const int b = blockIdx.x;            // elements 2b, 2b+1
    const int tid = threadIdx.x;
    const int w = tid >> 6;
    const int lane = tid & 63;
    const float* xA = inputs + (2 * b) * 12;
    const float* xB = inputs + (2 * b + 1) * 12;

    // ---- theta table: thread-invariant sincos computed once per block,
    // shared by BOTH elements.
    if (tid < 36) {
        const int l = tid / 12, q = tid % 12;
        float s, c; __sincosf(0.5f * PI_F * thetas[l * 24 + 2 * q], &s, &c);
        thTab[tid] = mkv(c, s);
    } else if (tid < 46) {
        const int j = tid - 36, l = j / 5, jj = j % 5;
        float s, c; __sincosf(PI_F * thetas[l * 24 + 2 * (11 - jj) + 1], &s, &c);
        thTab[tid] = mkv(c, s);
    }

    // ---- x-dependent encoding pieces, per stream (overlap with table fill)
    float phbA = 0.0f, phbB = 0.0f;
    #pragma unroll
    for (int k = 0; k < 6; ++k) {               // layout-A lane bit k <-> q(11-k)
        const bool s = (lane >> k) & 1;
        phbA += s ? xA[11 - k] : 0.0f;
        phbB += s ? xB[11 - k] : 0.0f;
    }
    float cAs, cAc; __sincosf(PI_F * phbA, &cAs, &cAc);
    float cBs, cBc; __sincosf(PI_F * phbB, &cBs, &cBc);
    float eAs, eAc; __sincosf(PI_F * xA[0], &eAs, &eAc);
    float eBs, eBc; __sincosf(PI_F * xB[0], &eBs, &eBc);
    v2f zrA[5], zrB[5];
    #pragma unroll
    for (int j = 0; j < 5; ++j) {               // layout-A reg bit j <-> q(5-j)
        float ss, cc;
        __sincosf(PI_F * xA[5 - j], &ss, &cc); zrA[j] = mkv(cc, ss);
        __sincosf(PI_F * xB[5 - j], &ss, &cc); zrB[j] = mkv(cc, ss);
    }

    __syncthreads();                            // table ready

    // ---- Encoding (closed form) with layer-0 Y_q0 folded in; 4-way chains,
    // both streams interleaved.
    v2f aA[NR], aB[NR];
    {
        v2f t0 = thTab[0];                      // (c0, s0) of 0.5*pi*theta0
        v2f FwA = w ? mkv(t0.y + t0.x * eAc,  t0.x * eAs)
                    : mkv(t0.x - t0.y * eAc, -t0.y * eAs);
        v2f FwB = w ? mkv(t0.y + t0.x * eBc,  t0.x * eBs)
                    : mkv(t0.x - t0.y * eBc, -t0.y * eBs);
        const v2f gA = cmul(FwA, mkv(cAc, cAs)) * 0.015625f;
        const v2f gB = cmul(FwB, mkv(cBc, cBs)) * 0.015625f;
        v2f cA[4], cB[4];
        cA[0] = gA;                              cB[0] = gB;
        cA[1] = cmul(gA, cmul(zrA[2], zrA[3]));  cB[1] = cmul(gB, cmul(zrB[2], zrB[3]));
        cA[2] = cmul(gA, cmul(zrA[3], zrA[4]));  cB[2] = cmul(gB, cmul(zrB[3], zrB[4]));
        cA[3] = cmul(gA, cmul(zrA[2], zrA[4]));  cB[3] = cmul(gB, cmul(zrB[2], zrB[4]));
        aA[0] = cA[0]; aA[12] = cA[1]; aA[24] = cA[2]; aA[20] = cA[3];
        aB[0] = cB[0]; aB[12] = cB[1]; aB[24] = cB[2]; aB[20] = cB[3];
        #pragma unroll
        for (int i = 1; i < 8; ++i) {
            #pragma unroll
            for (int m = 0; m < 4; ++m) {
                const int k = 8 * m + i;
                const int bit = __builtin_ctz(i);
                const int g = k ^ (k >> 1);
                cA[m] = ((g >> bit) & 1) ? cmul(cA[m], zrA[bit])
                                         : cmulc(cA[m], zrA[bit]);
                cB[m] = ((g >> bit) & 1) ? cmul(cB[m], zrB[bit])
                                         : cmulc(cB[m], zrB[bit]);
                aA[g] = cA[m];
                aB[g] = cB[m];
            }
        }
    }

    // ----- layer 0 -----
    ypowA2(aA, aB, &thTab[0]);
    { v2f t = thTab[6];  exchange_AB2<false>(aA, aB, buf, w, lane, t.x, t.y); }
    ypowB2(aA, aB, &thTab[0]);
    fused_z2(aA, aB, w, lane, thetas, &thTab[36]);
    { v2f t = thTab[12]; exchange_BA2(aA, aB, buf, w, lane, t.x, t.y); }

    // ----- layer 1 -----
    ypowA2(aA, aB, &thTab[12]);
    { v2f t = thTab[18]; exchange_AB2<true>(aA, aB, buf, w, lane, t.x, t.y); }
    ypowB2(aA, aB, &thTab[12]);
    fused_z2(aA, aB, w, lane, thetas + 24, &thTab[41]);
    { v2f t = thTab[24]; exchange_BA2(aA, aB, buf, w, lane, t.x, t.y); }

    // ----- layer 2 (no CNOT; Zs dropped — diagonal before |amp|^2) -----
    ypowA2(aA, aB, &thTab[24]);
    { v2f t = thTab[30]; exchange_AB2<true>(aA, aB, buf, w, lane, t.x, t.y); }
    ypowB2(aA, aB, &thTab[24]);

    // ---- Readout in layout B: b11=w(q0), lane bit k<->q(6-k), reg bit j<->q(11-j)
    float tpA = 0.0f, tpB = 0.0f;
    float DA[5] = {0,0,0,0,0}, DB[5] = {0,0,0,0,0};
    #pragma unroll
    for (int r = 0; r < NR; ++r) {
        const float pA = aA[r].x * aA[r].x + aA[r].y * aA[r].y;
        const float pB = aB[r].x * aB[r].x + aB[r].y * aB[r].y;
        tpA += pA; tpB += pB;
        #pragma unroll
        for (int j = 0; j < 5; ++j) {
            DA[j] += ((r >> j) & 1) ? -pA : pA;
            DB[j] += ((r >> j) & 1) ? -pB : pB;
        }
    }
    // q0: plain fold of totalP, sign by wave bit (both streams interleaved)
    {
        float TA = tpA, TB = tpB;
        TA += lane_xor_f<32>(TA); TB += lane_xor_f<32>(TB);
        TA += lane_xor_f<16>(TA); TB += lane_xor_f<16>(TB);
        TA += lane_xor_f<8>(TA);  TB += lane_xor_f<8>(TB);
        TA += lane_xor_f<4>(TA);  TB += lane_xor_f<4>(TB);
        TA += lane_xor_f<2>(TA);  TB += lane_xor_f<2>(TB);
        TA += lane_xor_f<1>(TA);  TB += lane_xor_f<1>(TB);
        if (lane == 0) {
            redBuf[0][w * 12 + 0] = w ? -TA : TA;
            redBuf[1][w * 12 + 0] = w ? -TB : TB;
        }
    }
    #pragma unroll
    for (int q = 1; q < 12; ++q) {
        float vA, vB;
        if (q <= 6) {
            const bool s = (lane >> (6 - q)) & 1;
            vA = s ? -tpA : tpA;
            vB = s ? -tpB : tpB;
        } else {
            vA = DA[11 - q];
            vB = DB[11 - q];
        }
        vA += lane_xor_f<32>(vA); vB += lane_xor_f<32>(vB);
        vA += lane_xor_f<16>(vA); vB += lane_xor_f<16>(vB);
        vA += lane_xor_f<8>(vA);  vB += lane_xor_f<8>(vB);
        vA += lane_xor_f<4>(vA);  vB += lane_xor_f<4>(vB);
        vA += lane_xor_f<2>(vA);  vB += lane_xor_f<2>(vB);
        vA += lane_xor_f<1>(vA);  vB += lane_xor_f<1>(vB);
        if (lane == 0) {
            redBuf[0][w * 12 + q] = vA;
            redBuf[1][w * 12 + q] = vB;
        }
    }
    __syncthreads();
    if (tid < 24) {
        const int s = tid / 12, q = tid % 12;
        out[(2 * b + s) * 12 + q] = redBuf[s][q] + redBuf[s][12 + q];
    }
}

extern "C" void kernel_launch(void* const* d_in, const int* in_sizes, int n_in,
                              void* d_out, int out_size, void* d_ws, size_t ws_size,
                              hipStream_t stream) {
    const float* inputs = (const float*)d_in[0];   // [1024,12] f32
    const float* thetas = (const float*)d_in[1];   // [72] f32
    float* out = (float*)d_out;                    // [1024,12] f32
    vqc_kernel<<<dim3(512), dim3(128), 0, stream>>>(inputs, thetas, out);
}

// Round 10
// 74.894 us; speedup vs baseline: 1.0418x; 1.0418x over previous
//
#include <hip/hip_runtime.h>

// VQC 12-qubit statevector, batch=1024. R10: ONE WAVE PER ELEMENT.
// 1024 blocks x 64 threads (1 wave), NR=64 v2f regs/thread. ZERO __syncthreads:
// every exchange is wave-local (in-order DS + s_waitcnt lgkmcnt(0)); the theta
// table is built and consumed by the same wave. R0-R9 evidence: the wall was
// never issue rate / occupancy / dep-depth — it was ~30-40 block-wide
// barrier/drain phases. This design has 5 wave-local drains total.
//
// Layouts (flat amp index X, qubit q <-> bit (11-q)):
//   A: b11..b6 = reg (q0..q5),  b5..b0 = lane (q6..q11)
//   B: b11..b6 = lane (q0..q5), b5..b0 = reg (q6..q11)
// With no wave bits and no lane-bit gates, ALL 36 Y gates are reg-pair gates
// and the exchanges are PURE permutations (no gather coefficients):
//   AB: plain 64x64 transpose. BA: CNOT-chain Gray permutation
//   (new[y] = old[y^(y>>1)], 12-bit): writer stores amp X at slot
//   (row,col) = (T_lo, T_hi), T = GrayInv12(X); reader at output y=(rp,lane)
//   reads (row,col) = (lane, rp) -> b128 reads at bank floor.
// Encoding: closed form amp = 2^-6 * cis(pi*sum_set x_q), no Y folded.
// Layer 2: no CNOT, Zs dropped (diagonal before |amp|^2). Readout in B.
//
// LDS: buf 64x66 v2f = 33,792B + thTab 48 v2f = 384B => 34,176B -> 4 blk/CU
// (1 wave/SIMD; zero TLP, pure straight-line ILP - 32 indep pairs per gate).

#define PI_F 3.14159265358979323846f
#define NR 64
#define PAD 66   // row stride (v2f): 528B rows -> 16B-aligned b128 pairs

typedef __attribute__((ext_vector_type(2))) float v2f;
typedef __attribute__((ext_vector_type(4))) float v4f;

__device__ __forceinline__ v2f mkv(float x, float y) { v2f r; r.x = x; r.y = y; return r; }
__device__ __forceinline__ v2f cmul(v2f a, v2f b) {   // complex a*b
    return a.x * b + a.y * mkv(-b.y, b.x);
}
__device__ __forceinline__ v2f cmulc(v2f a, v2f b) {  // a * conj(b)
    return a.x * mkv(b.x, -b.y) + a.y * mkv(b.y, b.x);
}

// ---- cross-lane xor primitives (readout trees only) ----
template<int M>
__device__ __forceinline__ float lane_xor_f(float v) {
    if constexpr (M == 1) {
        return __int_as_float(__builtin_amdgcn_update_dpp(
            0, __float_as_int(v), 0xB1, 0xF, 0xF, false));
    } else if constexpr (M == 2) {
        return __int_as_float(__builtin_amdgcn_update_dpp(
            0, __float_as_int(v), 0x4E, 0xF, 0xF, false));
    } else if constexpr (M == 4) {
        return __int_as_float(__builtin_amdgcn_ds_swizzle(__float_as_int(v), 0x101F));
    } else if constexpr (M == 8) {
        return __int_as_float(__builtin_amdgcn_ds_swizzle(__float_as_int(v), 0x201F));
    } else if constexpr (M == 16) {
        return __int_as_float(__builtin_amdgcn_ds_swizzle(__float_as_int(v), 0x401F));
    } else {
        return __shfl_xor(v, 32, 64);
    }
}

// Y gate on reg bit RB: 32 independent pairs, 4 pk-FMA each.
template<int RB>
__device__ __forceinline__ void ypow_reg(v2f (&a)[NR], v2f cs) {
    const float c = cs.x, s = cs.y;
    #pragma unroll
    for (int r0 = 0; r0 < NR; ++r0) {
        if ((r0 >> RB) & 1) continue;
        const int r1 = r0 | (1 << RB);
        v2f a0 = a[r0], a1 = a[r1];
        a[r0] = c * a0 - s * a1;
        a[r1] = s * a0 + c * a1;
    }
}

// Layout A: reg bit (5-j) <-> q j ; gates q0..q5 of layer table yt[0..5]
__device__ __forceinline__ void ypowA(v2f (&a)[NR], const v2f* __restrict__ yt) {
    ypow_reg<5>(a, yt[0]);  // q0
    ypow_reg<4>(a, yt[1]);  // q1
    ypow_reg<3>(a, yt[2]);  // q2
    ypow_reg<2>(a, yt[3]);  // q3
    ypow_reg<1>(a, yt[4]);  // q4
    ypow_reg<0>(a, yt[5]);  // q5
}
// Layout B: reg bit (11-q) ; gates q6..q11 of layer table yt[6..11]
__device__ __forceinline__ void ypowB(v2f (&a)[NR], const v2f* __restrict__ yt) {
    ypow_reg<5>(a, yt[6]);  // q6
    ypow_reg<4>(a, yt[7]);  // q7
    ypow_reg<3>(a, yt[8]);  // q8
    ypow_reg<2>(a, yt[9]);  // q9
    ypow_reg<1>(a, yt[10]); // q10
    ypow_reg<0>(a, yt[11]); // q11
}

// A->B: pure 64x64 transpose, wave-local. Write row r col lane (b64,
// conflict-free); read row lane col r' as 32x b128 (8/bank floor).
__device__ __forceinline__ void exchange_AB(v2f (&a)[NR], v2f* buf, int lane) {
    #pragma unroll
    for (int r = 0; r < NR; ++r)
        buf[r * PAD + lane] = a[r];
    asm volatile("s_waitcnt lgkmcnt(0)" ::: "memory");
    #pragma unroll
    for (int r2 = 0; r2 < NR; r2 += 2) {
        v4f p = *(const v4f*)(&buf[lane * PAD + r2]);
        a[r2]     = p.xy;
        a[r2 + 1] = p.zw;
    }
    asm volatile("" ::: "memory");   // reads stay before any later overwrite
}

// B->A with CNOT-chain Gray permutation. Writer: amp X = wlane<<6 | r
// (layout B); T = GrayInv12(X): T_hi = pre6(wlane), T_lo = pre6(r) ^
// (parity(wlane)?63:0). Store at (row,col) = (T_lo, T_hi). Reader: output
// y = rp<<6 | lane (layout A) needs slot T = y -> (row,col) = (lane, rp):
// 32x b128 at bank floor.
__device__ __forceinline__ void exchange_BA(v2f (&a)[NR], v2f* buf, int lane) {
    int u = lane; u ^= u >> 1; u ^= u >> 2; u ^= u >> 4; u &= 63;  // pre6(lane)
    const int maskb = (u & 1) ? 63 : 0;     // parity(lane) ? complement : id
    #pragma unroll
    for (int r = 0; r < NR; ++r) {
        int pr = r; pr ^= pr >> 1; pr ^= pr >> 2; pr ^= pr >> 4; pr &= 63;
        buf[(pr ^ maskb) * PAD + u] = a[r];
    }
    asm volatile("s_waitcnt lgkmcnt(0)" ::: "memory");
    #pragma unroll
    for (int r2 = 0; r2 < NR; r2 += 2) {
        v4f p = *(const v4f*)(&buf[lane * PAD + r2]);
        a[r2]     = p.xy;
        a[r2 + 1] = p.zw;
    }
    asm volatile("" ::: "memory");
}

// Gray-code starts for 8 sub-chains of 8 over 6 bits: g(8m) bit sets.
__device__ __forceinline__ void gray_starts(const v2f (&z)[6], v2f base,
                                            v2f (&curs)[8]) {
    const v2f z23 = cmul(z[2], z[3]);
    const v2f z45 = cmul(z[4], z[5]);  // careful: bits named by index into z
    // NOTE: z[j] multiplies when Gray bit j is set. g(8m) for m=1..7 are
    // 12={2,3}, 24={3,4}, 20={2,4}, 48={4,5}, 60={2,3,4,5}, 40={3,5}, 36={2,5}
    const v2f z34 = cmul(z[3], z[4]);
    const v2f z24 = cmul(z[2], z[4]);
    const v2f z35 = cmul(z[3], z[5]);
    const v2f z25 = cmul(z[2], z[5]);
    curs[0] = base;
    curs[1] = cmul(base, z23);
    curs[2] = cmul(base, z34);
    curs[3] = cmul(base, z24);
    curs[4] = cmul(base, z45);
    curs[5] = cmul(base, cmul(z23, z45));
    curs[6] = cmul(base, z35);
    curs[7] = cmul(base, z25);
}

__global__ __launch_bounds__(64) void vqc_kernel(
    const float* __restrict__ inputs,   // [1024,12]
    const float* __restrict__ thetas,   // [72] = [3][12][2]
    float* __restrict__ out)            // [1024,12]
{
    __shared__ __align__(16) v2f buf[NR * PAD];   // 33,792 B
    __shared__ v2f thTab[48];                     // 36 Y + 12 Z pairs

    const int b = blockIdx.x;
    const int lane = threadIdx.x;       // 64 threads = 1 wave
    const float* x = inputs + b * 12;

    // ---- theta table (built and consumed by the same wave; no barrier).
    // Y[l][q] = (cos,sin)(0.5*pi*th[l*24+2q])       at thTab[l*12+q]
    // Z[l][j] = cis(pi*th[l*24+2*(11-j)+1]), j=0..5 at thTab[36+l*6+j]
    if (lane < 36) {
        const int l = lane / 12, q = lane % 12;
        float s, c; __sincosf(0.5f * PI_F * thetas[l * 24 + 2 * q], &s, &c);
        thTab[lane] = mkv(c, s);
    } else if (lane < 48) {
        const int j = lane - 36, l = j / 6, jj = j % 6;
        float s, c; __sincosf(PI_F * thetas[l * 24 + 2 * (11 - jj) + 1], &s, &c);
        thTab[lane] = mkv(c, s);
    }

    // ---- Encoding (layout A): amp = 2^-6 * cis(pi * sum_{q set} x_q).
    // Lane bits = q6..q11 (lane bit k <-> q(11-k)); reg bits: bit j <-> q(5-j).
    float phl = 0.0f;
    #pragma unroll
    for (int k = 0; k < 6; ++k)
        phl += ((lane >> k) & 1) ? x[11 - k] : 0.0f;
    float ps, pc; __sincosf(PI_F * phl, &ps, &pc);
    v2f zr[6];
    #pragma unroll
    for (int j = 0; j < 6; ++j) {       // reg bit j <-> q(5-j)
        float ss, cc; __sincosf(PI_F * x[5 - j], &ss, &cc);
        zr[j] = mkv(cc, ss);
    }
    v2f a[NR];
    {
        const v2f base = mkv(pc, ps) * 0.015625f;
        v2f curs[8];
        gray_starts(zr, base, curs);
        a[0] = curs[0]; a[12] = curs[1]; a[24] = curs[2]; a[20] = curs[3];
        a[48] = curs[4]; a[60] = curs[5]; a[40] = curs[6]; a[36] = curs[7];
        #pragma unroll
        for (int i = 1; i < 8; ++i) {
            #pragma unroll
            for (int m = 0; m < 8; ++m) {
                const int k = 8 * m + i;
                const int bit = __builtin_ctz(i);
                const int g = k ^ (k >> 1);
                curs[m] = ((g >> bit) & 1) ? cmul(curs[m], zr[bit])
                                           : cmulc(curs[m], zr[bit]);
                a[g] = curs[m];
            }
        }
    }

    asm volatile("s_waitcnt lgkmcnt(0)" ::: "memory");   // table ready

    #pragma unroll
    for (int l = 0; l < 3; ++l) {
        const v2f* yt = &thTab[l * 12];
        ypowA(a, yt);                 // Y q0..q5 (reg gates, layout A)
        exchange_AB(a, buf, lane);    // -> layout B (pure transpose)
        ypowB(a, yt);                 // Y q6..q11 (reg gates, layout B)
        if (l < 2) {
            // fused Z all 12 qubits (layout B): lane bit k <-> q(5-k),
            // reg bit j <-> q(11-j).
            float alpha = 0.0f;
            #pragma unroll
            for (int k = 0; k < 6; ++k)
                alpha += ((lane >> k) & 1) ? thetas[l * 24 + 2 * (5 - k) + 1] : 0.0f;
            float zs, zc; __sincosf(PI_F * alpha, &zs, &zc);
            v2f zq[6];
            #pragma unroll
            for (int j = 0; j < 6; ++j) zq[j] = thTab[36 + l * 6 + j];
            v2f curs[8];
            gray_starts(zq, mkv(zc, zs), curs);
            a[0]  = cmul(a[0],  curs[0]); a[12] = cmul(a[12], curs[1]);
            a[24] = cmul(a[24], curs[2]); a[20] = cmul(a[20], curs[3]);
            a[48] = cmul(a[48], curs[4]); a[60] = cmul(a[60], curs[5]);
            a[40] = cmul(a[40], curs[6]); a[36] = cmul(a[36], curs[7]);
            #pragma unroll
            for (int i = 1; i < 8; ++i) {
                #pragma unroll
                for (int m = 0; m < 8; ++m) {
                    const int k = 8 * m + i;
                    const int bit = __builtin_ctz(i);
                    const int g = k ^ (k >> 1);
                    curs[m] = ((g >> bit) & 1) ? cmul(curs[m], zq[bit])
                                               : cmulc(curs[m], zq[bit]);
                    a[g] = cmul(a[g], curs[m]);
                }
            }
            exchange_BA(a, buf, lane);   // CNOT-chain Gray perm -> layout A
        }
    }

    // ---- Readout (layout B): lane bit k <-> q(5-k), reg bit j <-> q(11-j).
    float totalP = 0.0f;
    float D[6] = {0, 0, 0, 0, 0, 0};
    #pragma unroll
    for (int r = 0; r < NR; ++r) {
        const float p = a[r].x * a[r].x + a[r].y * a[r].y;
        totalP += p;
        #pragma unroll
        for (int j = 0; j < 6; ++j)
            D[j] += ((r >> j) & 1) ? -p : p;
    }
    float res = 0.0f;
    #pragma unroll
    for (int q = 0; q < 12; ++q) {
        float v;
        if (q <= 5) v = ((lane >> (5 - q)) & 1) ? -totalP : totalP;
        else        v = D[11 - q];
        v += lane_xor_f<32>(v);
        v += lane_xor_f<16>(v);
        v += lane_xor_f<8>(v);
        v += lane_xor_f<4>(v);
        v += lane_xor_f<2>(v);
        v += lane_xor_f<1>(v);
        if (lane == q) res = v;       // tree leaves full sum in every lane
    }
    if (lane < 12) out[b * 12 + lane] = res;
}

extern "C" void kernel_launch(void* const* d_in, const int* in_sizes, int n_in,
                              void* d_out, int out_size, void* d_ws, size_t ws_size,
                              hipStream_t stream) {
    const float* inputs = (const float*)d_in[0];   // [1024,12] f32
    const float* thetas = (const float*)d_in[1];   // [72] f32
    float* out = (float*)d_out;                    // [1024,12] f32
    vqc_kernel<<<dim3(1024), dim3(64), 0, stream>>>(inputs, thetas, out);
}

// Round 11
// 74.622 us; speedup vs baseline: 1.0456x; 1.0036x over previous
//
#include <hip/hip_runtime.h>

// VQC 12-qubit statevector, batch=1024, 128 threads/block (2 waves), NR=32.
// R11 = R7 (best verified: 74.6us bench, VGPR 96, zero spill) + BLOCK STAGGER.
// R10 post-mortem: three distinct structures (0-barrier/1-wave, 8-barrier/
// 2-wave, 4-wave) all converge at ~35us kernel with VALU ~10us + DS ~6.5us of
// actual pipe work. Shared feature: gate phases (VALU) and exchange phases
// (DS) alternate in GLOBAL LOCKSTEP across the 4 co-resident blocks per CU
// (identical code, simultaneous start) -> the two pipes never overlap across
// blocks. Fix under test: stagger co-resident blocks (bid, bid+256, +512,
// +768 share a CU under round-robin dispatch) by 0/768/1536/2304 cycles via
// s_sleep so one block's DS phase hides under another's VALU phase.
//
// Structure (unchanged from R7):
//   Layout A: b11=w(q0), b10..b6=reg(q1..q5), b5..b0=lane(q6..q11)
//   Layout B: b11=w(q0), b10..b5=lane(q1..q6), b4..b0=reg(q7..q11)
// Per layer: Y q1..5 reg [A]; A->B exch (fuses Y_q6; wave-local lgkm drain);
// Y q7..11 reg [B]; fused Z (4-way Gray chains); B->A exch (fuses CNOT-chain
// perm + next layer's Y_q0). Layer-0 Y_q0 folded into closed-form encoding;
// layer-2 Zs dropped. LDS theta-table (46 sincos pairs, built once/block).

#define PI_F 3.14159265358979323846f
#define NR 32
#define PAD 66   // even: 528B rows -> b128 pairs stay 16B-aligned

typedef __attribute__((ext_vector_type(2))) float v2f;
typedef __attribute__((ext_vector_type(4))) float v4f;

__device__ __forceinline__ v2f mkv(float x, float y) { v2f r; r.x = x; r.y = y; return r; }
__device__ __forceinline__ v2f cmul(v2f a, v2f b) {   // complex a*b
    return a.x * b + a.y * mkv(-b.y, b.x);
}
__device__ __forceinline__ v2f cmulc(v2f a, v2f b) {  // a * conj(b)
    return a.x * mkv(b.x, -b.y) + a.y * mkv(b.y, b.x);
}

// ---- cross-lane xor primitives (readout only) ----
template<int M>
__device__ __forceinline__ float lane_xor_f(float v) {
    if constexpr (M == 1) {        // quad_perm [1,0,3,2]
        return __int_as_float(__builtin_amdgcn_update_dpp(
            0, __float_as_int(v), 0xB1, 0xF, 0xF, false));
    } else if constexpr (M == 2) { // quad_perm [2,3,0,1]
        return __int_as_float(__builtin_amdgcn_update_dpp(
            0, __float_as_int(v), 0x4E, 0xF, 0xF, false));
    } else if constexpr (M == 4) {
        return __int_as_float(__builtin_amdgcn_ds_swizzle(__float_as_int(v), 0x101F));
    } else if constexpr (M == 8) {
        return __int_as_float(__builtin_amdgcn_ds_swizzle(__float_as_int(v), 0x201F));
    } else if constexpr (M == 16) {
        return __int_as_float(__builtin_amdgcn_ds_swizzle(__float_as_int(v), 0x401F));
    } else {                       // M == 32: cross-half
        return __shfl_xor(v, 32, 64);
    }
}

template<int RB>
__device__ __forceinline__ void ypow_reg(v2f (&a)[NR], float c, float s) {
    #pragma unroll
    for (int r0 = 0; r0 < NR; ++r0) {
        if ((r0 >> RB) & 1) continue;
        const int r1 = r0 | (1 << RB);
        v2f a0 = a[r0], a1 = a[r1];
        a[r0] = c * a0 - s * a1;
        a[r1] = s * a0 + c * a1;
    }
}

// yt = &thTab[l*12]; layout A: q1..q5 -> reg bits 4..0
__device__ __forceinline__ void ypowA(v2f (&a)[NR], const v2f* __restrict__ yt) {
    { v2f t = yt[1]; ypow_reg<4>(a, t.x, t.y); }
    { v2f t = yt[2]; ypow_reg<3>(a, t.x, t.y); }
    { v2f t = yt[3]; ypow_reg<2>(a, t.x, t.y); }
    { v2f t = yt[4]; ypow_reg<1>(a, t.x, t.y); }
    { v2f t = yt[5]; ypow_reg<0>(a, t.x, t.y); }
}
// layout B: q7..q11 -> reg bits 4..0
__device__ __forceinline__ void ypowB(v2f (&a)[NR], const v2f* __restrict__ yt) {
    { v2f t = yt[7];  ypow_reg<4>(a, t.x, t.y); }
    { v2f t = yt[8];  ypow_reg<3>(a, t.x, t.y); }
    { v2f t = yt[9];  ypow_reg<2>(a, t.x, t.y); }
    { v2f t = yt[10]; ypow_reg<1>(a, t.x, t.y); }
    { v2f t = yt[11]; ypow_reg<0>(a, t.x, t.y); }
}

// A->B transpose, fusing Y on q6 (b5). Wave-local (b11 untouched).
template<bool PRE_SYNC>
__device__ __forceinline__ void exchange_AB(v2f (&a)[NR], v2f* buf,
                                            int w, int lane, float c6, float s6) {
    v2f* wb = buf + w * (NR * PAD);
    if (PRE_SYNC) __syncthreads();         // prev BA's cross-wave reads done
    #pragma unroll
    for (int r = 0; r < NR; ++r)           // slot = [b10..b6 | b4..b0 | b5]
        wb[r * PAD + (lane & 31) * 2 + (lane >> 5)] = a[r];
    asm volatile("s_waitcnt lgkmcnt(0)" ::: "memory");   // wave-local drain
    const int g = lane >> 1;               // b10..b6 of output
    const float k0 = (lane & 1) ? s6 : c6;
    const float k1 = (lane & 1) ? c6 : -s6;
    #pragma unroll
    for (int r = 0; r < NR; ++r) {
        v4f p = *(const v4f*)(&wb[g * PAD + r * 2]);   // (b5=0, b5=1) pair
        a[r] = k0 * p.xy + k1 * p.zw;
    }
}

// B->A transpose, fusing the CNOT-chain permutation (new[y] = old[y ^ (y>>1)])
// and the NEXT layer's Y_q0 (mixes b11; pairs stored adjacent).
__device__ __forceinline__ void exchange_BA(v2f (&a)[NR], v2f* buf,
                                            int w, int lane, float c0, float s0) {
    __syncthreads();                       // all waves' AB-region reads done
    const int p6w = lane ^ (w << 5);       // (x10^x11)<<5 | x9..x5 for this writer
    #pragma unroll
    for (int r = 0; r < NR; ++r)           // slot = p6*PAD + (x4..x0)*2 + x11
        buf[p6w * PAD + r * 2 + w] = a[r];
    __syncthreads();
    const float k0 = w ? s0 : c0;
    const float k1 = w ? c0 : -s0;
    #pragma unroll
    for (int rp = 0; rp < NR; ++rp) {
        const int ylow = (rp << 6) | lane;         // b10..b0 of output index
        const int t = ylow ^ (ylow >> 1);          // Gray inverse (11 bits)
        const int base = (t >> 5) * PAD + (t & 31) * 2;
        v4f p = *(const v4f*)(&buf[base]);         // (b11=0, b11=1) pair
        a[rp] = k0 * p.xy + k1 * p.zw;
    }
}

// Fused Z for all 12 qubits, layout B. Gray-code running complex product,
// split into 4 parallel sub-chains (k = 8m..8m+7) -> dependent depth ~10.
__device__ __forceinline__ void fused_z_B(v2f (&a)[NR], int w, int lane,
                                          const float* __restrict__ th,
                                          const v2f* __restrict__ zt) {
    float alpha = w ? th[1] : 0.0f;
    #pragma unroll
    for (int k = 0; k < 6; ++k)                 // lane bit k <-> q(6-k)
        alpha += ((lane >> k) & 1) ? th[2*(6-k)+1] : 0.0f;
    float zs, zc; __sincosf(PI_F * alpha, &zs, &zc);
    v2f zq[5];
    #pragma unroll
    for (int j = 0; j < 5; ++j) zq[j] = zt[j];  // reg bit j <-> q(11-j)
    const v2f base = mkv(zc, zs);
    v2f curs[4];
    curs[0] = base;
    curs[1] = cmul(base, cmul(zq[2], zq[3]));   // g(8)  = 12
    curs[2] = cmul(base, cmul(zq[3], zq[4]));   // g(16) = 24
    curs[3] = cmul(base, cmul(zq[2], zq[4]));   // g(24) = 20
    a[0]  = cmul(a[0],  curs[0]);
    a[12] = cmul(a[12], curs[1]);
    a[24] = cmul(a[24], curs[2]);
    a[20] = cmul(a[20], curs[3]);
    #pragma unroll
    for (int i = 1; i < 8; ++i) {
        #pragma unroll
        for (int m = 0; m < 4; ++m) {
            const int k = 8 * m + i;
            const int bit = __builtin_ctz(i);
            const int g = k ^ (k >> 1);
            curs[m] = ((g >> bit) & 1) ? cmul(curs[m], zq[bit])
                                       : cmulc(curs[m], zq[bit]);
            a[g] = cmul(a[g], curs[m]);
        }
    }
}

__global__ __launch_bounds__(128) void vqc_kernel(
    const float* __restrict__ inputs,   // [1024,12]
    const float* __restrict__ thetas,   // [72] = [3][12][2]
    float* __restrict__ out)            // [1024,12]
{
    __shared__ __align__(16) v2f buf[64 * PAD];   // 33,792 B exchange buffer
    __shared__ v2f thTab[46];                     // 36 Y pairs + 10 Z pairs
    __shared__ float redBuf[24];

    const int b = blockIdx.x;
    const int tid = threadIdx.x;
    const int w = tid >> 6;
    const int lane = tid & 63;
    const float* x = inputs + b * 12;

    // ---- pipe-phase stagger: co-resident blocks (bid, bid+256, +512, +768
    // land on one CU under round-robin dispatch) offset by ~768 cyc each so
    // their VALU (gate) and DS (exchange) phases interleave across blocks.
    {
        const int skey = (b >> 8) & 3;            // wave-uniform
        for (int i = 0; i < skey; ++i) __builtin_amdgcn_s_sleep(12);
    }

    // ---- theta table: thread-invariant sincos computed once per block.
    if (tid < 36) {
        const int l = tid / 12, q = tid % 12;
        float s, c; __sincosf(0.5f * PI_F * thetas[l * 24 + 2 * q], &s, &c);
        thTab[tid] = mkv(c, s);
    } else if (tid < 46) {
        const int j = tid - 36, l = j / 5, jj = j % 5;
        float s, c; __sincosf(PI_F * thetas[l * 24 + 2 * (11 - jj) + 1], &s, &c);
        thTab[tid] = mkv(c, s);
    }

    // ---- x-dependent encoding pieces (overlap with table fill, pre-barrier)
    float phb = 0.0f;
    #pragma unroll
    for (int k = 0; k < 6; ++k)                 // layout-A lane bit k <-> q(11-k)
        phb += ((lane >> k) & 1) ? x[11 - k] : 0.0f;
    float cbs, cbc; __sincosf(PI_F * phb, &cbs, &cbc);
    v2f cisb = mkv(cbc, cbs);
    float es, ec; __sincosf(PI_F * x[0], &es, &ec);
    v2f zr[5];
    #pragma unroll
    for (int j = 0; j < 5; ++j) {               // layout-A reg bit j <-> q(5-j)
        float ss, cc; __sincosf(PI_F * x[5 - j], &ss, &cc);
        zr[j] = mkv(cc, ss);
    }

    __syncthreads();                            // table ready

    // ---- Encoding (closed form) with layer-0 Y_q0 folded in; 4-way chains.
    v2f a[NR];
    {
        v2f t0 = thTab[0];                      // (c0, s0) of 0.5*pi*theta0
        v2f Fw = w ? mkv(t0.y + t0.x * ec,  t0.x * es)
                   : mkv(t0.x - t0.y * ec, -t0.y * es);
        const v2f g0 = cmul(Fw, cisb) * 0.015625f;
        v2f curs[4];
        curs[0] = g0;
        curs[1] = cmul(g0, cmul(zr[2], zr[3]));   // g(8)  = 12
        curs[2] = cmul(g0, cmul(zr[3], zr[4]));   // g(16) = 24
        curs[3] = cmul(g0, cmul(zr[2], zr[4]));   // g(24) = 20
        a[0] = curs[0]; a[12] = curs[1]; a[24] = curs[2]; a[20] = curs[3];
        #pragma unroll
        for (int i = 1; i < 8; ++i) {
            #pragma unroll
            for (int m = 0; m < 4; ++m) {
                const int k = 8 * m + i;
                const int bit = __builtin_ctz(i);
                const int g = k ^ (k >> 1);
                curs[m] = ((g >> bit) & 1) ? cmul(curs[m], zr[bit])
                                           : cmulc(curs[m], zr[bit]);
                a[g] = curs[m];
            }
        }
    }

    const float* th0 = thetas;
    const float* th1 = thetas + 24;
    const float* th2 = thetas + 48;

    // ----- layer 0 -----
    ypowA(a, &thTab[0]);
    { v2f t = thTab[6];  exchange_AB<false>(a, buf, w, lane, t.x, t.y); }
    ypowB(a, &thTab[0]);
    fused_z_B(a, w, lane, th0, &thTab[36]);
    { v2f t = thTab[12]; exchange_BA(a, buf, w, lane, t.x, t.y); }   // next-layer Y_q0

    // ----- layer 1 -----
    ypowA(a, &thTab[12]);
    { v2f t = thTab[18]; exchange_AB<true>(a, buf, w, lane, t.x, t.y); }
    ypowB(a, &thTab[12]);
    fused_z_B(a, w, lane, th1, &thTab[41]);
    { v2f t = thTab[24]; exchange_BA(a, buf, w, lane, t.x, t.y); }   // next-layer Y_q0

    // ----- layer 2 (no CNOT; Zs dropped — diagonal before |amp|^2) -----
    ypowA(a, &thTab[24]);
    { v2f t = thTab[30]; exchange_AB<true>(a, buf, w, lane, t.x, t.y); }
    ypowB(a, &thTab[24]);

    // ---- Readout in layout B: b11=w(q0), lane bit k<->q(6-k), reg bit j<->q(11-j)
    float totalP = 0.0f;
    float D[5] = {0, 0, 0, 0, 0};
    #pragma unroll
    for (int r = 0; r < NR; ++r) {
        const float p = a[r].x * a[r].x + a[r].y * a[r].y;
        totalP += p;
        #pragma unroll
        for (int j = 0; j < 5; ++j)
            D[j] += ((r >> j) & 1) ? -p : p;
    }
    // q0: plain fold of totalP, sign by wave bit
    {
        float T = totalP;
        T += lane_xor_f<32>(T);
        T += lane_xor_f<16>(T);
        T += lane_xor_f<8>(T);
        T += lane_xor_f<4>(T);
        T += lane_xor_f<2>(T);
        T += lane_xor_f<1>(T);
        if (lane == 0) redBuf[w * 12 + 0] = w ? -T : T;
    }
    #pragma unroll
    for (int q = 1; q < 12; ++q) {
        float v;
        if (q <= 6)  v = ((lane >> (6 - q)) & 1) ? -totalP : totalP;
        else         v = D[11 - q];
        v += lane_xor_f<32>(v);
        v += lane_xor_f<16>(v);
        v += lane_xor_f<8>(v);
        v += lane_xor_f<4>(v);
        v += lane_xor_f<2>(v);
        v += lane_xor_f<1>(v);
        if (lane == 0) redBuf[w * 12 + q] = v;
    }
    __syncthreads();
    if (tid < 12) out[b * 12 + tid] = redBuf[tid] + redBuf[12 + tid];
}

extern "C" void kernel_launch(void* const* d_in, const int* in_sizes, int n_in,
                              void* d_out, int out_size, void* d_ws, size_t ws_size,
                              hipStream_t stream) {
    const float* inputs = (const float*)d_in[0];   // [1024,12] f32
    const float* thetas = (const float*)d_in[1];   // [72] f32
    float* out = (float*)d_out;                    // [1024,12] f32
    vqc_kernel<<<dim3(1024), dim3(128), 0, stream>>>(inputs, thetas, out);
}